// Round 4
// baseline (261.688 us; speedup 1.0000x reference)
//
#include <hip/hip_runtime.h>
#include <stdint.h>

// Varlen GQA causal flash-attention fwd, bf16x3-split MFMA (32x32x16).
// R4: (a) prepack does the V transpose through LDS (coalesced global R/W);
// (b) main kernel single-buffers one 32KB tile -> 3 blocks/CU (was 2);
// (c) defer-max softmax (skip O-rescale unless row max moved > 8).

#define NH 16
#define NKVH 4
#define HD 128
#define NB 8
#define SCALE 0.08838834764831844f
#define NEG_INF -1.0e10f
#define NT32 204                 // 6528/32 global 32-token tiles
#define TILE_IMG 32768           // kh8K|kl8K|vh8K|vl8K
#define WS_NEED ((size_t)NKVH * NT32 * TILE_IMG)   // 26,738,688 B

typedef short bf16x8 __attribute__((ext_vector_type(8)));
typedef float f32x16 __attribute__((ext_vector_type(16)));
typedef unsigned short us4 __attribute__((ext_vector_type(4)));
typedef unsigned short us8 __attribute__((ext_vector_type(8)));

union FragU { us8 u; bf16x8 b; };

__device__ __forceinline__ unsigned short f2bf(float f) {
    uint32_t u = __float_as_uint(f);
    u += 0x7fffu + ((u >> 16) & 1u);   // RNE
    return (unsigned short)(u >> 16);
}
__device__ __forceinline__ float bf2f(unsigned short h) {
    return __uint_as_float(((uint32_t)h) << 16);
}

// ---------------- geometry tables ----------------
// seq lens /32: {32,28,24,20,32,16,30,22}; cumsum:
__constant__ int c_s32[NB] = {0, 32, 60, 84, 104, 136, 152, 182};
// 204 (b, qt32) work items, LPT order (qt desc, b asc)
__constant__ signed char c_b[NT32] = {
  0,4, 0,4, 0,4,6, 0,4,6, 0,1,4,6, 0,1,4,6, 0,1,4,6, 0,1,4,6,
  0,1,2,4,6, 0,1,2,4,6, 0,1,2,4,6,7, 0,1,2,4,6,7,
  0,1,2,3,4,6,7, 0,1,2,3,4,6,7, 0,1,2,3,4,6,7, 0,1,2,3,4,6,7,
  0,1,2,3,4,5,6,7, 0,1,2,3,4,5,6,7, 0,1,2,3,4,5,6,7, 0,1,2,3,4,5,6,7,
  0,1,2,3,4,5,6,7, 0,1,2,3,4,5,6,7, 0,1,2,3,4,5,6,7, 0,1,2,3,4,5,6,7,
  0,1,2,3,4,5,6,7, 0,1,2,3,4,5,6,7, 0,1,2,3,4,5,6,7, 0,1,2,3,4,5,6,7,
  0,1,2,3,4,5,6,7, 0,1,2,3,4,5,6,7, 0,1,2,3,4,5,6,7, 0,1,2,3,4,5,6,7};
__constant__ signed char c_qt[NT32] = {
  31,31, 30,30, 29,29,29, 28,28,28, 27,27,27,27, 26,26,26,26, 25,25,25,25,
  24,24,24,24, 23,23,23,23,23, 22,22,22,22,22, 21,21,21,21,21,21,
  20,20,20,20,20,20, 19,19,19,19,19,19,19, 18,18,18,18,18,18,18,
  17,17,17,17,17,17,17, 16,16,16,16,16,16,16,
  15,15,15,15,15,15,15,15, 14,14,14,14,14,14,14,14, 13,13,13,13,13,13,13,13,
  12,12,12,12,12,12,12,12, 11,11,11,11,11,11,11,11, 10,10,10,10,10,10,10,10,
  9,9,9,9,9,9,9,9, 8,8,8,8,8,8,8,8, 7,7,7,7,7,7,7,7, 6,6,6,6,6,6,6,6,
  5,5,5,5,5,5,5,5, 4,4,4,4,4,4,4,4, 3,3,3,3,3,3,3,3, 2,2,2,2,2,2,2,2,
  1,1,1,1,1,1,1,1, 0,0,0,0,0,0,0,0};

// ---------------- pre-pass: pack K/V tiles into ws ----------------
// K: direct (reads and writes both coalesced). V: transpose through LDS so
// global reads (float4 along d) AND writes (linear 16B image dump) coalesce.
__global__ __launch_bounds__(256, 4)
void prepack(const float* __restrict__ K, const float* __restrict__ V,
             unsigned char* __restrict__ ws)
{
    __shared__ unsigned char vs[16384];   // V^T hi (8KB) | lo (8KB)
    const int gt  = blockIdx.x;
    const int kvh = blockIdx.y;
    const int tid = threadIdx.x;
    unsigned char* img = ws + ((size_t)(kvh * NT32 + gt)) * TILE_IMG;

    // K: [32 key][128 d] bf16 hi/lo, swizzle ^((key&7)<<4)
    #pragma unroll
    for (int i = 0; i < 4; ++i) {
        int chunk = tid + 256 * i;                // 0..1023
        int key = chunk >> 5, dq = chunk & 31;
        const float* kp = K + ((size_t)(gt * 32 + key) * NKVH + kvh) * HD + dq * 4;
        float4 f = *reinterpret_cast<const float4*>(kp);
        us4 hi4, lo4;
        hi4[0]=f2bf(f.x); hi4[1]=f2bf(f.y); hi4[2]=f2bf(f.z); hi4[3]=f2bf(f.w);
        lo4[0]=f2bf(f.x-bf2f(hi4[0])); lo4[1]=f2bf(f.y-bf2f(hi4[1]));
        lo4[2]=f2bf(f.z-bf2f(hi4[2])); lo4[3]=f2bf(f.w-bf2f(hi4[3]));
        int off = (key * 256 + dq * 8) ^ ((key & 7) << 4);
        *reinterpret_cast<us4*>(img + off)        = hi4;
        *reinterpret_cast<us4*>(img + 8192 + off) = lo4;
    }
    // V: coalesced float4 read -> bf16 hi/lo scatter into LDS V^T layout
    {
        const int token = tid >> 3;
        const int dg    = (tid & 7) * 16;
        const float* vp = V + ((size_t)(gt * 32 + token) * NKVH + kvh) * HD + dg;
        #pragma unroll
        for (int j = 0; j < 4; ++j) {
            float4 f = *reinterpret_cast<const float4*>(vp + j * 4);
            float e[4] = {f.x, f.y, f.z, f.w};
            #pragma unroll
            for (int q = 0; q < 4; ++q) {
                int d = dg + j * 4 + q;
                unsigned short h = f2bf(e[q]);
                unsigned short l = f2bf(e[q] - bf2f(h));
                int off = (d * 64 + token * 2) ^ ((d & 7) << 4);
                *reinterpret_cast<unsigned short*>(vs + off)        = h;
                *reinterpret_cast<unsigned short*>(vs + 8192 + off) = l;
            }
        }
    }
    __syncthreads();
    // dump LDS image linearly: fully coalesced 16B stores
    #pragma unroll
    for (int i = 0; i < 4; ++i) {
        int off = i * 4096 + tid * 16;
        *reinterpret_cast<us8*>(img + 16384 + off) =
            *reinterpret_cast<const us8*>(vs + off);
    }
}

// ---------------- main kernel ----------------
#define GLOAD_LDS(g, l) \
    __builtin_amdgcn_global_load_lds((const __attribute__((address_space(1))) void*)(g), \
                                     (__attribute__((address_space(3))) void*)(l), 16, 0, 0)

__global__ __launch_bounds__(256, 3)
void fa_fwd_ws(const float* __restrict__ Q, const unsigned char* __restrict__ ws,
               float* __restrict__ O)
{
    __shared__ unsigned char smem[TILE_IMG];   // 32 KB single tile buffer

    const int bx  = blockIdx.x;
    const int kvh = blockIdx.y;
    const int b   = c_b[bx], qt = c_qt[bx];
    const int gx  = c_s32[b] + qt;          // global q 32-tile
    const int nt  = qt + 1;                 // K-tiles (BK=32)

    const int tid  = threadIdx.x;
    const int w    = tid >> 6;
    const int lane = tid & 63;
    const int c    = lane & 31;             // q-row / key-row / d-row
    const int hib  = lane >> 5;
    const int swz  = (c & 7) << 4;
    const int hi16 = hib << 4;

    const int head  = kvh * 4 + w;
    const int token = gx * 32 + c;

    const unsigned char* imgbase = ws + (size_t)(kvh * NT32 + c_s32[b]) * TILE_IMG;

    // ---- Q fragments: row c, dims 16*ks + 8*hib + j, scaled, hi/lo split ----
    bf16x8 qfh[8], qfl[8];
    {
        const float* qp = Q + ((size_t)token * NH + head) * HD + (hib ? 8 : 0);
        #pragma unroll
        for (int ks = 0; ks < 8; ++ks) {
            float4 f0 = *reinterpret_cast<const float4*>(qp + ks * 16);
            float4 f1 = *reinterpret_cast<const float4*>(qp + ks * 16 + 4);
            float e[8] = {f0.x, f0.y, f0.z, f0.w, f1.x, f1.y, f1.z, f1.w};
            FragU uh, ul;
            #pragma unroll
            for (int j = 0; j < 8; ++j) {
                float s = e[j] * SCALE;
                unsigned short h = f2bf(s);
                uh.u[j] = h;
                ul.u[j] = f2bf(s - bf2f(h));
            }
            qfh[ks] = uh.b; qfl[ks] = ul.b;
        }
    }

    f32x16 oacc[4];
    #pragma unroll
    for (int d = 0; d < 4; ++d)
        #pragma unroll
        for (int r = 0; r < 16; ++r) oacc[d][r] = 0.f;
    float mrun = -1.0e30f, lrun = 0.f;

    for (int t = 0; t < nt; ++t) {
        const unsigned char* img = imgbase + (size_t)t * TILE_IMG;
        __syncthreads();   // all waves done reading smem (previous tile)
        #pragma unroll
        for (int j = 0; j < 8; ++j)
            GLOAD_LDS(img + j * 4096 + w * 1024 + (lane << 4),
                      &smem[j * 4096 + w * 1024]);
        __syncthreads();   // stage complete (vmcnt drained before barrier)

        // ---- S^T = K · Q^T ----
        f32x16 sacc;
        #pragma unroll
        for (int r = 0; r < 16; ++r) sacc[r] = 0.f;
        __builtin_amdgcn_s_setprio(1);
        #pragma unroll
        for (int ks = 0; ks < 8; ++ks) {
            int koff = (c * 256 + ks * 32 + hi16) ^ swz;
            bf16x8 kh = *reinterpret_cast<const bf16x8*>(smem + koff);
            bf16x8 kl = *reinterpret_cast<const bf16x8*>(smem + 8192 + koff);
            sacc = __builtin_amdgcn_mfma_f32_32x32x16_bf16(kh, qfh[ks], sacc, 0, 0, 0);
            sacc = __builtin_amdgcn_mfma_f32_32x32x16_bf16(kl, qfh[ks], sacc, 0, 0, 0);
            sacc = __builtin_amdgcn_mfma_f32_32x32x16_bf16(kh, qfl[ks], sacc, 0, 0, 0);
        }
        __builtin_amdgcn_s_setprio(0);

        // ---- causal mask (diagonal tile: t == qt) ----
        if (t == nt - 1) {
            #pragma unroll
            for (int r = 0; r < 16; ++r) {
                int keyl = (r & 3) + 8 * (r >> 2) + 4 * hib;
                if (keyl > c) sacc[r] = NEG_INF;
            }
        }

        // ---- online softmax with defer-max (THR=8) ----
        float tm = -1.0e30f;
        #pragma unroll
        for (int r = 0; r < 16; ++r) tm = fmaxf(tm, sacc[r]);
        tm = fmaxf(tm, __shfl_xor(tm, 32));
        if (!__all(tm <= mrun + 8.f)) {
            const float mnew = fmaxf(mrun, tm);
            const float corr = __expf(mrun - mnew);
            lrun *= corr;
            #pragma unroll
            for (int d = 0; d < 4; ++d)
                #pragma unroll
                for (int r = 0; r < 16; ++r) oacc[d][r] *= corr;
            mrun = mnew;
        }
        float psum = 0.f;
        #pragma unroll
        for (int r = 0; r < 16; ++r) {
            float e = __expf(sacc[r] - mrun);
            sacc[r] = e;
            psum += e;
        }
        psum += __shfl_xor(psum, 32);
        lrun += psum;

        // ---- P^T B-fragments in-register (half-swap), hi/lo split ----
        bf16x8 pfh[2], pfl[2];
        #pragma unroll
        for (int s = 0; s < 2; ++s) {
            FragU uh, ul;
            #pragma unroll
            for (int bb = 0; bb < 4; ++bb) {
                float own  = hib ? sacc[8*s + 4 + bb] : sacc[8*s + bb];
                float send = hib ? sacc[8*s + bb]     : sacc[8*s + 4 + bb];
                float x = __shfl_xor(send, 32);
                float e0 = hib ? x : own;       // element bb   (from half 0)
                float e1 = hib ? own : x;       // element 4+bb (from half 1)
                unsigned short h0_ = f2bf(e0), h1_ = f2bf(e1);
                uh.u[bb]     = h0_; ul.u[bb]     = f2bf(e0 - bf2f(h0_));
                uh.u[4 + bb] = h1_; ul.u[4 + bb] = f2bf(e1 - bf2f(h1_));
            }
            pfh[s] = uh.b; pfl[s] = ul.b;
        }

        // ---- O^T += V^T · P^T ----
        __builtin_amdgcn_s_setprio(1);
        #pragma unroll
        for (int db = 0; db < 4; ++db) {
            #pragma unroll
            for (int s = 0; s < 2; ++s) {
                int voff = ((db * 32 + c) * 64 + s * 32 + hi16) ^ swz;
                bf16x8 vh = *reinterpret_cast<const bf16x8*>(smem + 16384 + voff);
                bf16x8 vl = *reinterpret_cast<const bf16x8*>(smem + 24576 + voff);
                oacc[db] = __builtin_amdgcn_mfma_f32_32x32x16_bf16(vh, pfh[s], oacc[db], 0, 0, 0);
                oacc[db] = __builtin_amdgcn_mfma_f32_32x32x16_bf16(vl, pfh[s], oacc[db], 0, 0, 0);
                oacc[db] = __builtin_amdgcn_mfma_f32_32x32x16_bf16(vh, pfl[s], oacc[db], 0, 0, 0);
            }
        }
        __builtin_amdgcn_s_setprio(0);
    }

    // ---- epilogue: direct float4 stores (r-groups of 4 are consecutive d) ----
    const float inv = 1.f / lrun;
    float* op = O + ((size_t)token * NH + head) * HD;
    #pragma unroll
    for (int db = 0; db < 4; ++db)
        #pragma unroll
        for (int i = 0; i < 4; ++i) {
            float4 r;
            r.x = oacc[db][4*i+0] * inv;
            r.y = oacc[db][4*i+1] * inv;
            r.z = oacc[db][4*i+2] * inv;
            r.w = oacc[db][4*i+3] * inv;
            *reinterpret_cast<float4*>(op + db * 32 + 8 * i + 4 * hib) = r;
        }
}

// ---------------- fallback (Round-2 kernel, used if ws too small) ----------------
__constant__ int c_cu_fb[NB + 1] = {0, 1024, 1920, 2688, 3328, 4352, 4864, 5824, 6528};
__constant__ signed char c_pb_fb[102] = {
  0,4, 0,4,6, 0,1,4,6, 0,1,4,6, 0,1,2,4,6, 0,1,2,4,6,7,
  0,1,2,3,4,6,7, 0,1,2,3,4,6,7, 0,1,2,3,4,5,6,7, 0,1,2,3,4,5,6,7,
  0,1,2,3,4,5,6,7, 0,1,2,3,4,5,6,7, 0,1,2,3,4,5,6,7, 0,1,2,3,4,5,6,7,
  0,1,2,3,4,5,6,7, 0,1,2,3,4,5,6,7};
__constant__ signed char c_pqt_fb[102] = {
  15,15, 14,14,14, 13,13,13,13, 12,12,12,12, 11,11,11,11,11, 10,10,10,10,10,10,
  9,9,9,9,9,9,9, 8,8,8,8,8,8,8, 7,7,7,7,7,7,7,7, 6,6,6,6,6,6,6,6,
  5,5,5,5,5,5,5,5, 4,4,4,4,4,4,4,4, 3,3,3,3,3,3,3,3, 2,2,2,2,2,2,2,2,
  1,1,1,1,1,1,1,1, 0,0,0,0,0,0,0,0};

union SharedU {
    struct { unsigned short kh[64 * 128], kl[64 * 128], vh[128 * 64], vl[128 * 64]; } kv;
    struct { float o[4][32 * 132]; } ep;
};

__global__ __launch_bounds__(256, 2)
void fa_fwd_fb(const float* __restrict__ Q, const float* __restrict__ K,
               const float* __restrict__ V, float* __restrict__ O)
{
    __shared__ SharedU smem;
    const int b    = c_pb_fb[blockIdx.x];
    const int qt   = c_pqt_fb[blockIdx.x];
    const int seq0 = c_cu_fb[b];
    const int q0   = qt * 64;
    const int nt   = qt + 1;
    const int hk = blockIdx.y >> 1;
    const int h0 = hk * 4 + (blockIdx.y & 1) * 2;
    const int tid  = threadIdx.x;
    const int w    = tid >> 6;
    const int lane = tid & 63;
    const int c    = lane & 31;
    const int hib  = lane >> 5;
    const int c7   = c & 7;
    const int hi16 = hib << 4;
    const int head  = h0 + (w >> 1);
    const int qbase = q0 + (w & 1) * 32;
    const int qpos  = qbase + c;

    bf16x8 qfh[8], qfl[8];
    {
        const float* qp = Q + ((size_t)(seq0 + qbase + c) * NH + head) * HD + (hib ? 8 : 0);
        #pragma unroll
        for (int ks = 0; ks < 8; ++ks) {
            float4 f0 = *reinterpret_cast<const float4*>(qp + ks * 16);
            float4 f1 = *reinterpret_cast<const float4*>(qp + ks * 16 + 4);
            float e[8] = {f0.x, f0.y, f0.z, f0.w, f1.x, f1.y, f1.z, f1.w};
            FragU uh, ul;
            #pragma unroll
            for (int j = 0; j < 8; ++j) {
                float s = e[j] * SCALE;
                unsigned short h = f2bf(s);
                uh.u[j] = h; ul.u[j] = f2bf(s - bf2f(h));
            }
            qfh[ks] = uh.b; qfl[ks] = ul.b;
        }
    }
    f32x16 oacc[4];
    #pragma unroll
    for (int d = 0; d < 4; ++d)
        #pragma unroll
        for (int r = 0; r < 16; ++r) oacc[d][r] = 0.f;
    float mrun = -1.0e30f, lrun = 0.f;

    for (int t = 0; t < nt; ++t) {
        const int kg0 = seq0 + t * 64;
        __syncthreads();
        #pragma unroll
        for (int i = 0; i < 8; ++i) {
            int chunk = tid + 256 * i;
            int key = chunk >> 5, dq = chunk & 31;
            const float* kp = K + ((size_t)(kg0 + key) * NKVH + hk) * HD + dq * 4;
            float4 f = *reinterpret_cast<const float4*>(kp);
            us4 hi4, lo4;
            hi4[0]=f2bf(f.x); hi4[1]=f2bf(f.y); hi4[2]=f2bf(f.z); hi4[3]=f2bf(f.w);
            lo4[0]=f2bf(f.x-bf2f(hi4[0])); lo4[1]=f2bf(f.y-bf2f(hi4[1]));
            lo4[2]=f2bf(f.z-bf2f(hi4[2])); lo4[3]=f2bf(f.w-bf2f(hi4[3]));
            int off = (key * 256 + dq * 8) ^ ((key & 7) << 4);
            *reinterpret_cast<us4*>((char*)smem.kv.kh + off) = hi4;
            *reinterpret_cast<us4*>((char*)smem.kv.kl + off) = lo4;
        }
        {
            const int d = tid & 127, kb2 = tid >> 7;
            const float* vp = V + ((size_t)(kg0 + kb2 * 32) * NKVH + hk) * HD + d;
            #pragma unroll
            for (int mq = 0; mq < 8; ++mq) {
                float f0 = vp[(mq*4+0) * (NKVH*HD)];
                float f1 = vp[(mq*4+1) * (NKVH*HD)];
                float f2 = vp[(mq*4+2) * (NKVH*HD)];
                float f3 = vp[(mq*4+3) * (NKVH*HD)];
                us4 hi4, lo4;
                hi4[0]=f2bf(f0); hi4[1]=f2bf(f1); hi4[2]=f2bf(f2); hi4[3]=f2bf(f3);
                lo4[0]=f2bf(f0-bf2f(hi4[0])); lo4[1]=f2bf(f1-bf2f(hi4[1]));
                lo4[2]=f2bf(f2-bf2f(hi4[2])); lo4[3]=f2bf(f3-bf2f(hi4[3]));
                int off = (d * 128 + (kb2 * 32 + mq * 4) * 2) ^ ((d & 7) << 4);
                *reinterpret_cast<us4*>((char*)smem.kv.vh + off) = hi4;
                *reinterpret_cast<us4*>((char*)smem.kv.vl + off) = lo4;
            }
        }
        __syncthreads();

        f32x16 sacc[2];
        #pragma unroll
        for (int kb = 0; kb < 2; ++kb)
            #pragma unroll
            for (int r = 0; r < 16; ++r) sacc[kb][r] = 0.f;
        #pragma unroll
        for (int ks = 0; ks < 8; ++ks) {
            #pragma unroll
            for (int kb = 0; kb < 2; ++kb) {
                int off = ((kb * 32 + c) * 256 + ks * 32 + hi16) ^ (c7 << 4);
                bf16x8 kh = *reinterpret_cast<bf16x8*>((char*)smem.kv.kh + off);
                bf16x8 kl = *reinterpret_cast<bf16x8*>((char*)smem.kv.kl + off);
                sacc[kb] = __builtin_amdgcn_mfma_f32_32x32x16_bf16(kh, qfh[ks], sacc[kb], 0, 0, 0);
                sacc[kb] = __builtin_amdgcn_mfma_f32_32x32x16_bf16(kl, qfh[ks], sacc[kb], 0, 0, 0);
                sacc[kb] = __builtin_amdgcn_mfma_f32_32x32x16_bf16(kh, qfl[ks], sacc[kb], 0, 0, 0);
            }
        }
        if (t == nt - 1) {
            #pragma unroll
            for (int kb = 0; kb < 2; ++kb)
                #pragma unroll
                for (int r = 0; r < 16; ++r) {
                    int keyl = kb * 32 + (r & 3) + 8 * (r >> 2) + 4 * hib;
                    if (t * 64 + keyl > qpos) sacc[kb][r] = NEG_INF;
                }
        }
        float tm = -1.0e30f;
        #pragma unroll
        for (int kb = 0; kb < 2; ++kb)
            #pragma unroll
            for (int r = 0; r < 16; ++r) tm = fmaxf(tm, sacc[kb][r]);
        tm = fmaxf(tm, __shfl_xor(tm, 32));
        const float mnew = fmaxf(mrun, tm);
        const float corr = __expf(mrun - mnew);
        float psum = 0.f;
        #pragma unroll
        for (int kb = 0; kb < 2; ++kb)
            #pragma unroll
            for (int r = 0; r < 16; ++r) {
                float e = __expf(sacc[kb][r] - mnew);
                sacc[kb][r] = e; psum += e;
            }
        psum += __shfl_xor(psum, 32);
        lrun = lrun * corr + psum;
        mrun = mnew;
        #pragma unroll
        for (int d = 0; d < 4; ++d)
            #pragma unroll
            for (int r = 0; r < 16; ++r) oacc[d][r] *= corr;

        bf16x8 pfh[4], pfl[4];
        #pragma unroll
        for (int s = 0; s < 4; ++s) {
            const int kb = s >> 1, sh = s & 1;
            FragU uh, ul;
            #pragma unroll
            for (int bb = 0; bb < 4; ++bb) {
                float own  = hib ? sacc[kb][8*sh + 4 + bb] : sacc[kb][8*sh + bb];
                float send = hib ? sacc[kb][8*sh + bb]     : sacc[kb][8*sh + 4 + bb];
                float x = __shfl_xor(send, 32);
                float e0 = hib ? x : own;
                float e1 = hib ? own : x;
                unsigned short h0_ = f2bf(e0), h1_ = f2bf(e1);
                uh.u[bb]     = h0_; ul.u[bb]     = f2bf(e0 - bf2f(h0_));
                uh.u[4 + bb] = h1_; ul.u[4 + bb] = f2bf(e1 - bf2f(h1_));
            }
            pfh[s] = uh.b; pfl[s] = ul.b;
        }
        #pragma unroll
        for (int db = 0; db < 4; ++db) {
            #pragma unroll
            for (int s = 0; s < 4; ++s) {
                int off = ((db * 32 + c) * 128 + s * 32 + hi16) ^ (c7 << 4);
                bf16x8 vh = *reinterpret_cast<bf16x8*>((char*)smem.kv.vh + off);
                bf16x8 vl = *reinterpret_cast<bf16x8*>((char*)smem.kv.vl + off);
                oacc[db] = __builtin_amdgcn_mfma_f32_32x32x16_bf16(vh, pfh[s], oacc[db], 0, 0, 0);
                oacc[db] = __builtin_amdgcn_mfma_f32_32x32x16_bf16(vl, pfh[s], oacc[db], 0, 0, 0);
                oacc[db] = __builtin_amdgcn_mfma_f32_32x32x16_bf16(vh, pfl[s], oacc[db], 0, 0, 0);
            }
        }
    }
    __syncthreads();
    {
        const float inv = 1.f / lrun;
        float* orow = smem.ep.o[w];
        #pragma unroll
        for (int db = 0; db < 4; ++db)
            #pragma unroll
            for (int r = 0; r < 16; ++r) {
                int d = db * 32 + (r & 3) + 8 * (r >> 2) + 4 * hib;
                orow[c * 132 + d] = oacc[db][r] * inv;
            }
        #pragma unroll
        for (int i = 0; i < 16; ++i) {
            int chunk = lane + 64 * i;
            int row = chunk >> 5, c16 = chunk & 31;
            float4 val = *reinterpret_cast<float4*>(orow + row * 132 + c16 * 4);
            int qtok = seq0 + qbase + row;
            *reinterpret_cast<float4*>(O + ((size_t)qtok * NH + head) * HD + c16 * 4) = val;
        }
    }
}

extern "C" void kernel_launch(void* const* d_in, const int* in_sizes, int n_in,
                              void* d_out, int out_size, void* d_ws, size_t ws_size,
                              hipStream_t stream) {
    const float* q = (const float*)d_in[0];
    const float* k = (const float*)d_in[1];
    const float* v = (const float*)d_in[2];
    float* out = (float*)d_out;

    if (ws_size >= WS_NEED) {
        dim3 gp(NT32, NKVH, 1);
        hipLaunchKernelGGL(prepack, gp, dim3(256, 1, 1), 0, stream,
                           k, v, (unsigned char*)d_ws);
        dim3 gm(NT32, NKVH, 1);
        hipLaunchKernelGGL(fa_fwd_ws, gm, dim3(256, 1, 1), 0, stream,
                           q, (const unsigned char*)d_ws, out);
    } else {
        dim3 grid(102, 8, 1);
        hipLaunchKernelGGL(fa_fwd_fb, grid, dim3(256, 1, 1), 0, stream,
                           q, k, v, out);
    }
}

// Round 5
// 225.753 us; speedup vs baseline: 1.1592x; 1.1592x over previous
//
#include <hip/hip_runtime.h>
#include <stdint.h>

// Varlen GQA causal flash-attention fwd, bf16x3-split MFMA (32x32x16).
// R5: ws image stored in FRAGMENT-LINEAR order; main kernel has NO LDS and
// NO barriers -- every MFMA operand is a coalesced 1KB/wave global load from
// the (L1/L2-resident) prepacked image, read straight into registers.
// Block = 4 independent waves = 4 heads of one kv head, one 32-row q tile.

#define NH 16
#define NKVH 4
#define HD 128
#define NB 8
#define SCALE 0.08838834764831844f
#define NEG_INF -1.0e10f
#define NT32 204                 // 6528/32 global 32-token tiles
#define TILE_IMG 32768           // KH 8K | KL 8K | VH 8K | VL 8K
#define WS_NEED ((size_t)NKVH * NT32 * TILE_IMG)   // 26,738,688 B

typedef short bf16x8 __attribute__((ext_vector_type(8)));
typedef float f32x16 __attribute__((ext_vector_type(16)));
typedef unsigned short us8 __attribute__((ext_vector_type(8)));

union FragU { us8 u; bf16x8 b; };

__device__ __forceinline__ unsigned short f2bf(float f) {
    uint32_t u = __float_as_uint(f);
    u += 0x7fffu + ((u >> 16) & 1u);   // RNE
    return (unsigned short)(u >> 16);
}
__device__ __forceinline__ float bf2f(unsigned short h) {
    return __uint_as_float(((uint32_t)h) << 16);
}

// ---------------- geometry tables ----------------
// seq lens /32: {32,28,24,20,32,16,30,22}; cumsum:
__constant__ int c_s32[NB] = {0, 32, 60, 84, 104, 136, 152, 182};
// 204 (b, qt32) work items, LPT order (qt desc, b asc)
__constant__ signed char c_b[NT32] = {
  0,4, 0,4, 0,4,6, 0,4,6, 0,1,4,6, 0,1,4,6, 0,1,4,6, 0,1,4,6,
  0,1,2,4,6, 0,1,2,4,6, 0,1,2,4,6,7, 0,1,2,4,6,7,
  0,1,2,3,4,6,7, 0,1,2,3,4,6,7, 0,1,2,3,4,6,7, 0,1,2,3,4,6,7,
  0,1,2,3,4,5,6,7, 0,1,2,3,4,5,6,7, 0,1,2,3,4,5,6,7, 0,1,2,3,4,5,6,7,
  0,1,2,3,4,5,6,7, 0,1,2,3,4,5,6,7, 0,1,2,3,4,5,6,7, 0,1,2,3,4,5,6,7,
  0,1,2,3,4,5,6,7, 0,1,2,3,4,5,6,7, 0,1,2,3,4,5,6,7, 0,1,2,3,4,5,6,7,
  0,1,2,3,4,5,6,7, 0,1,2,3,4,5,6,7, 0,1,2,3,4,5,6,7, 0,1,2,3,4,5,6,7};
__constant__ signed char c_qt[NT32] = {
  31,31, 30,30, 29,29,29, 28,28,28, 27,27,27,27, 26,26,26,26, 25,25,25,25,
  24,24,24,24, 23,23,23,23,23, 22,22,22,22,22, 21,21,21,21,21,21,
  20,20,20,20,20,20, 19,19,19,19,19,19,19, 18,18,18,18,18,18,18,
  17,17,17,17,17,17,17, 16,16,16,16,16,16,16,
  15,15,15,15,15,15,15,15, 14,14,14,14,14,14,14,14, 13,13,13,13,13,13,13,13,
  12,12,12,12,12,12,12,12, 11,11,11,11,11,11,11,11, 10,10,10,10,10,10,10,10,
  9,9,9,9,9,9,9,9, 8,8,8,8,8,8,8,8, 7,7,7,7,7,7,7,7, 6,6,6,6,6,6,6,6,
  5,5,5,5,5,5,5,5, 4,4,4,4,4,4,4,4, 3,3,3,3,3,3,3,3, 2,2,2,2,2,2,2,2,
  1,1,1,1,1,1,1,1, 0,0,0,0,0,0,0,0};

// ---------------- pre-pass: pack K/V into fragment-linear images ----------------
// Layout per (kvh, 32-token tile) image (32KB):
//   KH[ks][tok][hib]  : ks*1024 + tok*32 + hib*16       (ks=dims/16, 8 slices)
//   KL                : 8192 + same
//   VH[db][s][c][hib] : 16384 + db*2048 + s*1024 + c*32 + hib*16
//                       holds V[key = s*16+hib*8+j][d = db*32+c]  (transposed)
//   VL                : 24576 + same
// Built in LDS (scatter), dumped linearly -> coalesced global R/W both sides.
__global__ __launch_bounds__(256, 4)
void prepack(const float* __restrict__ K, const float* __restrict__ V,
             unsigned char* __restrict__ ws)
{
    __shared__ unsigned char img[TILE_IMG];
    const int gt  = blockIdx.x;
    const int kvh = blockIdx.y;
    const int tid = threadIdx.x;
    const int tok = tid >> 3;          // 0..31
    const int seg = tid & 7;           // 16-dim segment = ks
    unsigned char* gimg = ws + ((size_t)(kvh * NT32 + gt)) * TILE_IMG;

    // --- K: read 16 floats (row tok, dims seg*16..+16), write frag-linear ---
    {
        const float* kp = K + ((size_t)(gt * 32 + tok) * NKVH + kvh) * HD + seg * 16;
        float e[16];
        #pragma unroll
        for (int j = 0; j < 4; ++j)
            *reinterpret_cast<float4*>(&e[4 * j]) =
                *reinterpret_cast<const float4*>(kp + 4 * j);
        us8 h0, h1, l0, l1;
        #pragma unroll
        for (int j = 0; j < 8; ++j) {
            unsigned short h = f2bf(e[j]);
            h0[j] = h; l0[j] = f2bf(e[j] - bf2f(h));
            unsigned short g = f2bf(e[8 + j]);
            h1[j] = g; l1[j] = f2bf(e[8 + j] - bf2f(g));
        }
        int off = seg * 1024 + tok * 32;
        *reinterpret_cast<us8*>(img + off)              = h0;
        *reinterpret_cast<us8*>(img + off + 16)         = h1;
        *reinterpret_cast<us8*>(img + 8192 + off)       = l0;
        *reinterpret_cast<us8*>(img + 8192 + off + 16)  = l1;
    }
    // --- V: read 16 floats (row tok, dims seg*16..+16), transpose-scatter ---
    {
        const float* vp = V + ((size_t)(gt * 32 + tok) * NKVH + kvh) * HD + seg * 16;
        const int s   = tok >> 4;
        const int hib = (tok >> 3) & 1;
        const int jj  = tok & 7;
        const int kbase = 16384 + s * 1024 + hib * 16 + jj * 2;
        #pragma unroll
        for (int j = 0; j < 4; ++j) {
            float4 f = *reinterpret_cast<const float4*>(vp + 4 * j);
            float e[4] = {f.x, f.y, f.z, f.w};
            #pragma unroll
            for (int q = 0; q < 4; ++q) {
                int d  = seg * 16 + j * 4 + q;
                int db = d >> 5, cc = d & 31;
                int off = kbase + db * 2048 + cc * 32;
                unsigned short h = f2bf(e[q]);
                *reinterpret_cast<unsigned short*>(img + off)        = h;
                *reinterpret_cast<unsigned short*>(img + 8192 + off) = f2bf(e[q] - bf2f(h));
            }
        }
    }
    __syncthreads();
    // --- dump image linearly: fully coalesced 16B stores ---
    #pragma unroll
    for (int i = 0; i < 8; ++i) {
        int off = i * 4096 + tid * 16;
        *reinterpret_cast<us8*>(gimg + off) = *reinterpret_cast<const us8*>(img + off);
    }
}

// ---------------- main kernel: no LDS, no barriers ----------------
__global__ __launch_bounds__(256, 2)
void fa_fwd_reg(const float* __restrict__ Q, const unsigned char* __restrict__ ws,
                float* __restrict__ O)
{
    // XCD-aware decode: XCD pair (2k,2k+1) <- kv head k; LPT order preserved.
    const int x   = blockIdx.x;
    const int kvh = (x & 7) >> 1;
    const int i   = ((x >> 3) << 1) | (x & 1);
    const int b   = c_b[i], qt = c_qt[i];
    const int gx  = c_s32[b] + qt;          // global q 32-tile
    const int nt  = qt + 1;                 // K-tiles (BK=32)

    const int tid  = threadIdx.x;
    const int w    = tid >> 6;
    const int lane = tid & 63;
    const int c    = lane & 31;             // q-row / key-row / d-row
    const int hib  = lane >> 5;
    const int foff = c * 32 + hib * 16;     // per-lane fragment offset

    const int head  = kvh * 4 + w;
    const int token = gx * 32 + c;

    const unsigned char* imgbase = ws + (size_t)(kvh * NT32 + c_s32[b]) * TILE_IMG;

    // ---- Q fragments: row c, dims 16*ks + 8*hib + j, scaled, hi/lo split ----
    bf16x8 qfh[8], qfl[8];
    {
        const float* qp = Q + ((size_t)token * NH + head) * HD + (hib ? 8 : 0);
        #pragma unroll
        for (int ks = 0; ks < 8; ++ks) {
            float4 f0 = *reinterpret_cast<const float4*>(qp + ks * 16);
            float4 f1 = *reinterpret_cast<const float4*>(qp + ks * 16 + 4);
            float e[8] = {f0.x, f0.y, f0.z, f0.w, f1.x, f1.y, f1.z, f1.w};
            FragU uh, ul;
            #pragma unroll
            for (int j = 0; j < 8; ++j) {
                float s = e[j] * SCALE;
                unsigned short h = f2bf(s);
                uh.u[j] = h;
                ul.u[j] = f2bf(s - bf2f(h));
            }
            qfh[ks] = uh.b; qfl[ks] = ul.b;
        }
    }

    f32x16 oacc[4];
    #pragma unroll
    for (int d = 0; d < 4; ++d)
        #pragma unroll
        for (int r = 0; r < 16; ++r) oacc[d][r] = 0.f;
    float mrun = -1.0e30f, lrun = 0.f;

    for (int t = 0; t < nt; ++t) {
        const unsigned char* tb = imgbase + (size_t)t * TILE_IMG;

        // ---- K fragments: 16 coalesced 1KB/wave loads, straight to regs ----
        bf16x8 kh[8], kl[8];
        #pragma unroll
        for (int ks = 0; ks < 8; ++ks) {
            kh[ks] = *reinterpret_cast<const bf16x8*>(tb + ks * 1024 + foff);
            kl[ks] = *reinterpret_cast<const bf16x8*>(tb + 8192 + ks * 1024 + foff);
        }

        // ---- S^T = K . Q^T ----
        f32x16 sacc;
        #pragma unroll
        for (int r = 0; r < 16; ++r) sacc[r] = 0.f;
        __builtin_amdgcn_s_setprio(1);
        #pragma unroll
        for (int ks = 0; ks < 8; ++ks) {
            sacc = __builtin_amdgcn_mfma_f32_32x32x16_bf16(kh[ks], qfh[ks], sacc, 0, 0, 0);
            sacc = __builtin_amdgcn_mfma_f32_32x32x16_bf16(kl[ks], qfh[ks], sacc, 0, 0, 0);
            sacc = __builtin_amdgcn_mfma_f32_32x32x16_bf16(kh[ks], qfl[ks], sacc, 0, 0, 0);
        }
        __builtin_amdgcn_s_setprio(0);

        // ---- V fragments (independent of softmax -> latency hides under it) ----
        bf16x8 vh[8], vl[8];
        #pragma unroll
        for (int db = 0; db < 4; ++db)
            #pragma unroll
            for (int s = 0; s < 2; ++s) {
                int idx = db * 2 + s;
                int off = 16384 + db * 2048 + s * 1024 + foff;
                vh[idx] = *reinterpret_cast<const bf16x8*>(tb + off);
                vl[idx] = *reinterpret_cast<const bf16x8*>(tb + 8192 + off);
            }

        // ---- causal mask (diagonal tile: t == qt) ----
        if (t == nt - 1) {
            #pragma unroll
            for (int r = 0; r < 16; ++r) {
                int keyl = (r & 3) + 8 * (r >> 2) + 4 * hib;
                if (keyl > c) sacc[r] = NEG_INF;
            }
        }

        // ---- online softmax with defer-max (THR=8) ----
        float tm = -1.0e30f;
        #pragma unroll
        for (int r = 0; r < 16; ++r) tm = fmaxf(tm, sacc[r]);
        tm = fmaxf(tm, __shfl_xor(tm, 32));
        if (!__all(tm <= mrun + 8.f)) {
            const float mnew = fmaxf(mrun, tm);
            const float corr = __expf(mrun - mnew);
            lrun *= corr;
            #pragma unroll
            for (int d = 0; d < 4; ++d)
                #pragma unroll
                for (int r = 0; r < 16; ++r) oacc[d][r] *= corr;
            mrun = mnew;
        }
        float psum = 0.f;
        #pragma unroll
        for (int r = 0; r < 16; ++r) {
            float e = __expf(sacc[r] - mrun);
            sacc[r] = e;
            psum += e;
        }
        psum += __shfl_xor(psum, 32);
        lrun += psum;

        // ---- P^T B-fragments in-register (half-swap), hi/lo split ----
        bf16x8 pfh[2], pfl[2];
        #pragma unroll
        for (int s = 0; s < 2; ++s) {
            FragU uh, ul;
            #pragma unroll
            for (int bb = 0; bb < 4; ++bb) {
                float own  = hib ? sacc[8*s + 4 + bb] : sacc[8*s + bb];
                float send = hib ? sacc[8*s + bb]     : sacc[8*s + 4 + bb];
                float xch = __shfl_xor(send, 32);
                float e0 = hib ? xch : own;     // element bb   (from half 0)
                float e1 = hib ? own : xch;     // element 4+bb (from half 1)
                unsigned short h0_ = f2bf(e0), h1_ = f2bf(e1);
                uh.u[bb]     = h0_; ul.u[bb]     = f2bf(e0 - bf2f(h0_));
                uh.u[4 + bb] = h1_; ul.u[4 + bb] = f2bf(e1 - bf2f(h1_));
            }
            pfh[s] = uh.b; pfl[s] = ul.b;
        }

        // ---- O^T += V^T . P^T ----
        __builtin_amdgcn_s_setprio(1);
        #pragma unroll
        for (int db = 0; db < 4; ++db) {
            #pragma unroll
            for (int s = 0; s < 2; ++s) {
                int idx = db * 2 + s;
                oacc[db] = __builtin_amdgcn_mfma_f32_32x32x16_bf16(vh[idx], pfh[s], oacc[db], 0, 0, 0);
                oacc[db] = __builtin_amdgcn_mfma_f32_32x32x16_bf16(vl[idx], pfh[s], oacc[db], 0, 0, 0);
                oacc[db] = __builtin_amdgcn_mfma_f32_32x32x16_bf16(vh[idx], pfl[s], oacc[db], 0, 0, 0);
            }
        }
        __builtin_amdgcn_s_setprio(0);
    }

    // ---- epilogue: direct float4 stores (r-groups of 4 are consecutive d) ----
    const float inv = 1.f / lrun;
    float* op = O + ((size_t)token * NH + head) * HD;
    #pragma unroll
    for (int db = 0; db < 4; ++db)
        #pragma unroll
        for (int i2 = 0; i2 < 4; ++i2) {
            float4 r;
            r.x = oacc[db][4*i2+0] * inv;
            r.y = oacc[db][4*i2+1] * inv;
            r.z = oacc[db][4*i2+2] * inv;
            r.w = oacc[db][4*i2+3] * inv;
            *reinterpret_cast<float4*>(op + db * 32 + 8 * i2 + 4 * hib) = r;
        }
}

extern "C" void kernel_launch(void* const* d_in, const int* in_sizes, int n_in,
                              void* d_out, int out_size, void* d_ws, size_t ws_size,
                              hipStream_t stream) {
    const float* q = (const float*)d_in[0];
    const float* k = (const float*)d_in[1];
    const float* v = (const float*)d_in[2];
    float* out = (float*)d_out;
    // ws_size >= WS_NEED confirmed on this harness in R3/R4 (ws path executed).
    hipLaunchKernelGGL(prepack, dim3(NT32, NKVH, 1), dim3(256, 1, 1), 0, stream,
                       k, v, (unsigned char*)d_ws);
    hipLaunchKernelGGL(fa_fwd_reg, dim3(NT32 * NKVH, 1, 1), dim3(256, 1, 1), 0, stream,
                       q, (const unsigned char*)d_ws, out);
}